// Round 8
// baseline (120.057 us; speedup 1.0000x reference)
//
#include <hip/hip_runtime.h>
#include <hip/hip_cooperative_groups.h>

namespace cg = cooperative_groups;

#define B_ 8
#define C_ 512
#define D_ 128
#define LDG 132   // gram-phase LDS row stride (u16): 2-way-free gather
#define LDO 136   // out-phase LDS row stride (u16): b128-aligned rows
#define LDK 136   // fallback ks row stride
#define LDT 40    // fallback kt row stride

typedef __bf16 v8bf __attribute__((ext_vector_type(8)));
typedef float v4f __attribute__((ext_vector_type(4)));
typedef float fvec4 __attribute__((ext_vector_type(4)));
typedef unsigned short u16;
typedef u16 u16x4 __attribute__((ext_vector_type(4)));
typedef u16 u16x8 __attribute__((ext_vector_type(8)));

// f32 -> bf16 round-to-nearest-even
__device__ __forceinline__ u16 f2bf(float f) {
  unsigned u = __builtin_bit_cast(unsigned, f);
  u = u + 0x7FFFu + ((u >> 16) & 1u);
  return (u16)(u >> 16);
}
__device__ __forceinline__ float bf2f(u16 h) {
  unsigned u = ((unsigned)h) << 16;
  return __builtin_bit_cast(float, u);
}

// Coalesced 32x128 f32 chunk load: 4 fvec4/thread, 4B lane stride.
__device__ __forceinline__ void load_chunk(const float* __restrict__ Kbase,
                                           int tid, fvec4* pf) {
#pragma unroll
  for (int i = 0; i < 4; ++i)
    pf[i] = *(const fvec4*)(Kbase + i * 1024 + tid * 4);
}

// Write staged chunk to LDS row-major [32][stride] bf16 (b64 stores).
template <int STRIDE>
__device__ __forceinline__ void lds_put(const fvec4* pf, u16* ksb, int tid) {
  const int d0 = (tid & 31) * 4;
  const int rb = tid >> 5;
#pragma unroll
  for (int i = 0; i < 4; ++i) {
    const int r = i * 8 + rb;
    fvec4 v = pf[i];
    u16x4 u = {f2bf(v[0]), f2bf(v[1]), f2bf(v[2]), f2bf(v[3])};
    *(u16x4*)&ksb[r * STRIDE + d0] = u;
  }
}

// ================= fused cooperative kernel ================================
// grid (17,8), 256 thr / 4 waves, 1 block/CU.
// phase1: G[b][t] = K_t^T K_t (bf16)        [t<16 blocks]
// phase2: M'[b] = carry + exclusive prefix; tot[b] = sum  [flat<64 blocks]
// phase3: out = Q*M'^T + causal diag S*K    [t<16]; out2  [t==16]
__global__ __launch_bounds__(256, 1) void k_fused(
    const float* __restrict__ Q, const float* __restrict__ K,
    const float* __restrict__ carry, u16* __restrict__ G,
    u16* __restrict__ Mp, float* __restrict__ tot, float* __restrict__ out,
    float* __restrict__ out2) {
  cg::grid_group grid = cg::this_grid();
  const int t = blockIdx.x, b = blockIdx.y;
  const int tid = threadIdx.x;
  const int w = tid >> 6, l = tid & 63, lr = l & 15, lg = l >> 4;
  const int wr = (w & 1) * 16, wc = (w >> 1) * 64, sc0 = (w >> 1) * 16;
  const int r0 = t * 32;

  __shared__ u16 sh[5632];  // phase1: [32][LDG]; phase3: [32][LDO] + sl[32][40]

  fvec4 pf[4];  // K chunk, held in regs across phases
  v8bf qf[4];   // Q A-frags, held across phases

  // ---------------- phase 1: Gram ----------------
  if (t < 16) {
    load_chunk(K + (size_t)(b * C_ + r0) * D_, tid, pf);
    // Q A-frags: rows r0+wr+lr, k = kk*32 + 8lg + e (independent of G)
    const float* qrow = Q + (size_t)(b * C_ + r0 + wr + lr) * D_;
#pragma unroll
    for (int kk = 0; kk < 4; ++kk) {
      const float* p = qrow + kk * 32 + 8 * lg;
      fvec4 a = *(const fvec4*)p;
      fvec4 c2 = *(const fvec4*)(p + 4);
      u16 tmp[8] = {f2bf(a[0]),  f2bf(a[1]),  f2bf(a[2]),  f2bf(a[3]),
                    f2bf(c2[0]), f2bf(c2[1]), f2bf(c2[2]), f2bf(c2[3])};
      qf[kk] = *(const v8bf*)tmp;
    }
    lds_put<LDG>(pf, sh, tid);
    __syncthreads();
    // fr[n][e] = bf16(K[8lg+e][16n+lr]) from LDS
    v8bf fr[8];
#pragma unroll
    for (int n = 0; n < 8; ++n) {
      u16 tmp[8];
#pragma unroll
      for (int e = 0; e < 8; ++e) tmp[e] = sh[(8 * lg + e) * LDG + 16 * n + lr];
      fr[n] = *(const v8bf*)tmp;
    }
    u16* Gp = G + (size_t)(b * 16 + t) * 16384;
#pragma unroll
    for (int mi = 0; mi < 2; ++mi) {
      v8bf am = fr[2 * w + mi];
#pragma unroll
      for (int n = 0; n < 8; ++n) {
        v4f z = {0.f, 0.f, 0.f, 0.f};
        v4f a = __builtin_amdgcn_mfma_f32_16x16x32_bf16(am, fr[n], z, 0, 0, 0);
#pragma unroll
        for (int j = 0; j < 4; ++j)
          Gp[(size_t)(32 * w + 16 * mi + 4 * lg + j) * 128 + 16 * n + lr] =
              f2bf(a[j]);
      }
    }
  }

  __threadfence();
  grid.sync();
  __threadfence();

  // ---------------- phase 2: prefix (64 block-slices) ----------------
  {
    const int flat = b * 17 + t;  // 0..135
    if (flat < 64) {
      const int pb = flat >> 3;
      const int e0 = (flat & 7) * 2048 + tid * 8;
      fvec4 c0 = *(const fvec4*)(carry + e0);
      fvec4 c1 = *(const fvec4*)(carry + e0 + 4);
      float c[8] = {c0[0], c0[1], c0[2], c0[3], c1[0], c1[1], c1[2], c1[3]};
      float run[8] = {0.f, 0.f, 0.f, 0.f, 0.f, 0.f, 0.f, 0.f};
      const u16* gb = G + (size_t)pb * 16 * 16384 + e0;
      u16* mb = Mp + (size_t)pb * 16 * 16384 + e0;
#pragma unroll
      for (int tp = 0; tp < 16; ++tp) {
        u16x8 g = *(const u16x8*)(gb + (size_t)tp * 16384);
        u16x8 m;
#pragma unroll
        for (int i = 0; i < 8; ++i) m[i] = f2bf(c[i] + run[i]);
        *(u16x8*)(mb + (size_t)tp * 16384) = m;
#pragma unroll
        for (int i = 0; i < 8; ++i) run[i] += bf2f(g[i]);
      }
      fvec4 rr0 = {run[0], run[1], run[2], run[3]};
      fvec4 rr1 = {run[4], run[5], run[6], run[7]};
      *(fvec4*)(tot + (size_t)pb * 16384 + e0) = rr0;
      *(fvec4*)(tot + (size_t)pb * 16384 + e0 + 4) = rr1;
    }
  }

  __threadfence();
  grid.sync();
  __threadfence();

  // ---------------- phase 3: outputs ----------------
  if (t == 16) {  // out2 = carry + mean_b(tot)
    const int e0 = b * 2048 + tid * 8;
    fvec4 s0 = {0.f, 0.f, 0.f, 0.f}, s1 = {0.f, 0.f, 0.f, 0.f};
#pragma unroll
    for (int bb = 0; bb < 8; ++bb) {
      s0 += *(const fvec4*)(tot + (size_t)bb * 16384 + e0);
      s1 += *(const fvec4*)(tot + (size_t)bb * 16384 + e0 + 4);
    }
    fvec4 c0 = *(const fvec4*)(carry + e0);
    fvec4 c1 = *(const fvec4*)(carry + e0 + 4);
    *(fvec4*)(out2 + e0) = c0 + 0.125f * s0;
    *(fvec4*)(out2 + e0 + 4) = c1 + 0.125f * s1;
    return;
  }

  u16* ks = sh;             // [32][LDO]
  u16* sl = sh + 32 * LDO;  // [32][40]

  __syncthreads();  // everyone done with phase-1 LDS layout
  lds_put<LDO>(pf, ks, tid);

  // M' B-frags: direct bf16 b128 global loads (16 in flight)
  v8bf mf[16];
  {
    const u16* mp = Mp + (size_t)(b * 16 + t) * 16384;
#pragma unroll
    for (int kk = 0; kk < 4; ++kk)
#pragma unroll
      for (int n = 0; n < 4; ++n)
        mf[kk * 4 + n] = *(const v8bf*)(mp + (size_t)(wc + 16 * n + lr) * 128 +
                                        32 * kk + 8 * lg);
  }
  __syncthreads();

  // S-step B-frags: row-major b128 LDS reads
  v8bf sb[4];
#pragma unroll
  for (int kk = 0; kk < 4; ++kk)
    sb[kk] = *(const v8bf*)&ks[(sc0 + lr) * LDO + 32 * kk + 8 * lg];

  // PV B-frags: transposed LDS gather
  v8bf pb[4];
#pragma unroll
  for (int n = 0; n < 4; ++n) {
    u16 tmp[8];
#pragma unroll
    for (int e = 0; e < 8; ++e)
      tmp[e] = ks[(8 * lg + e) * LDO + wc + 16 * n + lr];
    pb[n] = *(const v8bf*)tmp;
  }

  // S tile = Q * Kchunk^T (diagonal, causal mask), hand off via LDS
  v4f sacc = {0.f, 0.f, 0.f, 0.f};
#pragma unroll
  for (int kk = 0; kk < 4; ++kk)
    sacc =
        __builtin_amdgcn_mfma_f32_16x16x32_bf16(qf[kk], sb[kk], sacc, 0, 0, 0);
#pragma unroll
  for (int j = 0; j < 4; ++j) {
    const int sr = wr + lg * 4 + j;
    const int sc = sc0 + lr;
    float v = sacc[j];
    if (sc > sr) v = 0.f;
    sl[sr * 40 + sc] = f2bf(v);
  }

  // acc = Q * M'^T (M' includes carry) — overlaps the barrier wait
  v4f acc[4] = {{0.f, 0.f, 0.f, 0.f}, {0.f, 0.f, 0.f, 0.f},
                {0.f, 0.f, 0.f, 0.f}, {0.f, 0.f, 0.f, 0.f}};
#pragma unroll
  for (int kk = 0; kk < 4; ++kk)
#pragma unroll
    for (int n = 0; n < 4; ++n)
      acc[n] = __builtin_amdgcn_mfma_f32_16x16x32_bf16(qf[kk], mf[kk * 4 + n],
                                                       acc[n], 0, 0, 0);
  __syncthreads();

  // PV: acc += S * Kchunk
  v8bf af = *(const v8bf*)&sl[(wr + lr) * 40 + lg * 8];
#pragma unroll
  for (int n = 0; n < 4; ++n)
    acc[n] =
        __builtin_amdgcn_mfma_f32_16x16x32_bf16(af, pb[n], acc[n], 0, 0, 0);

  // epilogue: C/D layout col = lane&15, row = 4*(lane>>4)+j
#pragma unroll
  for (int n = 0; n < 4; ++n)
#pragma unroll
    for (int j = 0; j < 4; ++j)
      out[(size_t)(b * C_ + r0 + wr + lg * 4 + j) * D_ + wc + n * 16 + lr] =
          acc[n][j];
}

// ================= round-6 three-kernel path (fallback) ====================
__global__ __launch_bounds__(256, 1) void k_gram(const float* __restrict__ K,
                                                 u16* __restrict__ G) {
  const int t = blockIdx.x, b = blockIdx.y;
  const int tid = threadIdx.x;
  const int w = tid >> 6, l = tid & 63, lr = l & 15, lg = l >> 4;

  __shared__ u16 ks[32 * LDG];

  fvec4 pf[4];
  load_chunk(K + (size_t)(b * C_ + t * 32) * D_, tid, pf);
  lds_put<LDG>(pf, ks, tid);
  __syncthreads();

  v8bf fr[8];
#pragma unroll
  for (int n = 0; n < 8; ++n) {
    u16 tmp[8];
#pragma unroll
    for (int e = 0; e < 8; ++e) tmp[e] = ks[(8 * lg + e) * LDG + 16 * n + lr];
    fr[n] = *(const v8bf*)tmp;
  }
  u16* Gp = G + (size_t)(b * 16 + t) * 16384;
#pragma unroll
  for (int mi = 0; mi < 2; ++mi) {
    v8bf am = fr[2 * w + mi];
#pragma unroll
    for (int n = 0; n < 8; ++n) {
      v4f z = {0.f, 0.f, 0.f, 0.f};
      v4f a = __builtin_amdgcn_mfma_f32_16x16x32_bf16(am, fr[n], z, 0, 0, 0);
#pragma unroll
      for (int j = 0; j < 4; ++j)
        Gp[(size_t)(32 * w + 16 * mi + 4 * lg + j) * 128 + 16 * n + lr] =
            f2bf(a[j]);
    }
  }
}

__global__ __launch_bounds__(256, 1) void k_prefix(
    const u16* __restrict__ G, const float* __restrict__ carry,
    u16* __restrict__ Mp, float* __restrict__ tot) {
  const int b = blockIdx.y;
  const int e0 = blockIdx.x * 2048 + threadIdx.x * 8;
  fvec4 c0 = *(const fvec4*)(carry + e0);
  fvec4 c1 = *(const fvec4*)(carry + e0 + 4);
  float c[8] = {c0[0], c0[1], c0[2], c0[3], c1[0], c1[1], c1[2], c1[3]};
  float run[8] = {0.f, 0.f, 0.f, 0.f, 0.f, 0.f, 0.f, 0.f};
  const u16* gb = G + (size_t)b * 16 * 16384 + e0;
  u16* mb = Mp + (size_t)b * 16 * 16384 + e0;
#pragma unroll
  for (int t = 0; t < 16; ++t) {
    u16x8 g = *(const u16x8*)(gb + (size_t)t * 16384);
    u16x8 m;
#pragma unroll
    for (int i = 0; i < 8; ++i) m[i] = f2bf(c[i] + run[i]);
    *(u16x8*)(mb + (size_t)t * 16384) = m;
#pragma unroll
    for (int i = 0; i < 8; ++i) run[i] += bf2f(g[i]);
  }
  fvec4 r0 = {run[0], run[1], run[2], run[3]};
  fvec4 r1 = {run[4], run[5], run[6], run[7]};
  *(fvec4*)(tot + (size_t)b * 16384 + e0) = r0;
  *(fvec4*)(tot + (size_t)b * 16384 + e0 + 4) = r1;
}

__global__ __launch_bounds__(256, 1) void k_out(
    const float* __restrict__ Q, const float* __restrict__ K,
    const u16* __restrict__ Mp, const float* __restrict__ tot,
    const float* __restrict__ carry, float* __restrict__ out,
    float* __restrict__ out2) {
  const int t = blockIdx.x, b = blockIdx.y;
  const int tid = threadIdx.x;

  if (t == 16) {
    const int e0 = b * 2048 + tid * 8;
    fvec4 s0 = {0.f, 0.f, 0.f, 0.f}, s1 = {0.f, 0.f, 0.f, 0.f};
#pragma unroll
    for (int bb = 0; bb < 8; ++bb) {
      s0 += *(const fvec4*)(tot + (size_t)bb * 16384 + e0);
      s1 += *(const fvec4*)(tot + (size_t)bb * 16384 + e0 + 4);
    }
    fvec4 c0 = *(const fvec4*)(carry + e0);
    fvec4 c1 = *(const fvec4*)(carry + e0 + 4);
    *(fvec4*)(out2 + e0) = c0 + 0.125f * s0;
    *(fvec4*)(out2 + e0 + 4) = c1 + 0.125f * s1;
    return;
  }

  const int w = tid >> 6, l = tid & 63, lr = l & 15, lg = l >> 4;
  const int wr = (w & 1) * 16, wc = (w >> 1) * 64, sc0 = (w >> 1) * 16;
  const int r0 = t * 32;

  __shared__ u16 ks[32 * LDO];
  __shared__ u16 sl[32 * 40];

  fvec4 pf[4];
  load_chunk(K + (size_t)(b * C_ + r0) * D_, tid, pf);

  v8bf qf[4];
  {
    const float* qrow = Q + (size_t)(b * C_ + r0 + wr + lr) * D_;
#pragma unroll
    for (int kk = 0; kk < 4; ++kk) {
      const float* p = qrow + kk * 32 + 8 * lg;
      fvec4 a = *(const fvec4*)p;
      fvec4 c2 = *(const fvec4*)(p + 4);
      u16 tmp[8] = {f2bf(a[0]),  f2bf(a[1]),  f2bf(a[2]),  f2bf(a[3]),
                    f2bf(c2[0]), f2bf(c2[1]), f2bf(c2[2]), f2bf(c2[3])};
      qf[kk] = *(const v8bf*)tmp;
    }
  }

  v8bf mf[16];
  {
    const u16* mp = Mp + (size_t)(b * 16 + t) * 16384;
#pragma unroll
    for (int kk = 0; kk < 4; ++kk)
#pragma unroll
      for (int n = 0; n < 4; ++n)
        mf[kk * 4 + n] = *(const v8bf*)(mp + (size_t)(wc + 16 * n + lr) * 128 +
                                        32 * kk + 8 * lg);
  }

  lds_put<LDO>(pf, ks, tid);
  __syncthreads();

  v8bf sb[4];
#pragma unroll
  for (int kk = 0; kk < 4; ++kk)
    sb[kk] = *(const v8bf*)&ks[(sc0 + lr) * LDO + 32 * kk + 8 * lg];

  v8bf pb[4];
#pragma unroll
  for (int n = 0; n < 4; ++n) {
    u16 tmp[8];
#pragma unroll
    for (int e = 0; e < 8; ++e)
      tmp[e] = ks[(8 * lg + e) * LDO + wc + 16 * n + lr];
    pb[n] = *(const v8bf*)tmp;
  }

  v4f sacc = {0.f, 0.f, 0.f, 0.f};
#pragma unroll
  for (int kk = 0; kk < 4; ++kk)
    sacc =
        __builtin_amdgcn_mfma_f32_16x16x32_bf16(qf[kk], sb[kk], sacc, 0, 0, 0);
#pragma unroll
  for (int j = 0; j < 4; ++j) {
    const int sr = wr + lg * 4 + j;
    const int sc = sc0 + lr;
    float v = sacc[j];
    if (sc > sr) v = 0.f;
    sl[sr * 40 + sc] = f2bf(v);
  }

  v4f acc[4] = {{0.f, 0.f, 0.f, 0.f}, {0.f, 0.f, 0.f, 0.f},
                {0.f, 0.f, 0.f, 0.f}, {0.f, 0.f, 0.f, 0.f}};
#pragma unroll
  for (int kk = 0; kk < 4; ++kk)
#pragma unroll
    for (int n = 0; n < 4; ++n)
      acc[n] = __builtin_amdgcn_mfma_f32_16x16x32_bf16(qf[kk], mf[kk * 4 + n],
                                                       acc[n], 0, 0, 0);
  __syncthreads();

  v8bf af = *(const v8bf*)&sl[(wr + lr) * 40 + lg * 8];
#pragma unroll
  for (int n = 0; n < 4; ++n)
    acc[n] =
        __builtin_amdgcn_mfma_f32_16x16x32_bf16(af, pb[n], acc[n], 0, 0, 0);

#pragma unroll
  for (int n = 0; n < 4; ++n)
#pragma unroll
    for (int j = 0; j < 4; ++j)
      out[(size_t)(b * C_ + r0 + wr + lg * 4 + j) * D_ + wc + n * 16 + lr] =
          acc[n][j];
}

extern "C" void kernel_launch(void* const* d_in, const int* in_sizes, int n_in,
                              void* d_out, int out_size, void* d_ws,
                              size_t ws_size, hipStream_t stream) {
  const float* Q = (const float*)d_in[0];
  const float* K = (const float*)d_in[1];
  const float* carry = (const float*)d_in[2];
  float* out = (float*)d_out;
  float* out2 = out + (size_t)B_ * C_ * D_;

  // ws: G bf16 [128][16384] | M' bf16 [128][16384] | tot f32 [8][16384]
  const size_t nGu = (size_t)128 * 16384;
  const size_t need = nGu * 2 * sizeof(u16) + (size_t)8 * 16384 * sizeof(float);
  if (ws_size < need) return;  // not expected (ws has been >=8.5MB all rounds)

  u16* G = (u16*)d_ws;
  u16* Mp = G + nGu;
  float* tot = (float*)(Mp + nGu);

  void* args[] = {(void*)&Q,  (void*)&K,   (void*)&carry, (void*)&G,
                  (void*)&Mp, (void*)&tot, (void*)&out,   (void*)&out2};
  hipError_t err = hipLaunchCooperativeKernel(
      reinterpret_cast<void*>(k_fused), dim3(17, 8), dim3(256, 1, 1), args, 0,
      stream);

  if (err != hipSuccess) {  // fallback: proven round-6 three-kernel path
    k_gram<<<dim3(16, 8), 256, 0, stream>>>(K, G);
    k_prefix<<<dim3(8, 8), 256, 0, stream>>>(G, carry, Mp, tot);
    k_out<<<dim3(17, 8), 256, 0, stream>>>(Q, K, Mp, tot, carry, out, out2);
  }
}

// Round 9
// 58.338 us; speedup vs baseline: 2.0580x; 2.0580x over previous
//
#include <hip/hip_runtime.h>

#define B_ 8
#define C_ 512
#define D_ 128
#define LDG 132   // gram-phase LDS row stride (u16): 2-way-free gather
#define LDO 136   // out-phase LDS row stride (u16): b128-aligned rows

typedef __bf16 v8bf __attribute__((ext_vector_type(8)));
typedef float v4f __attribute__((ext_vector_type(4)));
typedef float fvec4 __attribute__((ext_vector_type(4)));
typedef unsigned short u16;
typedef u16 u16x4 __attribute__((ext_vector_type(4)));
typedef u16 u16x8 __attribute__((ext_vector_type(8)));

// f32 -> bf16 round-to-nearest-even
__device__ __forceinline__ u16 f2bf(float f) {
  unsigned u = __builtin_bit_cast(unsigned, f);
  u = u + 0x7FFFu + ((u >> 16) & 1u);
  return (u16)(u >> 16);
}
__device__ __forceinline__ float bf2f(u16 h) {
  unsigned u = ((unsigned)h) << 16;
  return __builtin_bit_cast(float, u);
}

// Coalesced 32x128 f32 chunk load: 4 fvec4/thread, 4B lane stride.
__device__ __forceinline__ void load_chunk(const float* __restrict__ Kbase,
                                           int tid, fvec4* pf) {
#pragma unroll
  for (int i = 0; i < 4; ++i)
    pf[i] = *(const fvec4*)(Kbase + i * 1024 + tid * 4);
}

// Write staged chunk to LDS row-major [32][stride] bf16 (b64 stores).
template <int STRIDE>
__device__ __forceinline__ void lds_put(const fvec4* pf, u16* ksb, int tid) {
  const int d0 = (tid & 31) * 4;
  const int rb = tid >> 5;
#pragma unroll
  for (int i = 0; i < 4; ++i) {
    const int r = i * 8 + rb;
    fvec4 v = pf[i];
    u16x4 u = {f2bf(v[0]), f2bf(v[1]), f2bf(v[2]), f2bf(v[3])};
    *(u16x4*)&ksb[r * STRIDE + d0] = u;
  }
}

// Hand-rolled grid barrier: device-scope atomics on an L2-coherent counter.
// All 136 blocks are co-resident (grid <= CU count, 1 block/CU resources).
__device__ __forceinline__ void spin_barrier(unsigned* cnt, unsigned target) {
  __syncthreads();                 // all waves of this block done with phase
  if (threadIdx.x == 0) {
    __threadfence();               // release: publish phase writes
    atomicAdd(cnt, 1u);
    while (atomicAdd(cnt, 0u) < target) __builtin_amdgcn_s_sleep(2);
  }
  __syncthreads();
  __threadfence();                 // acquire: invalidate stale cached data
}

// ================= fused kernel (plain launch + spin barriers) =============
// grid (17,8), 256 thr / 4 waves, 1 block/CU.
// phase1: G[b][t] = K_t^T K_t (bf16)                      [t<16]
// phase2: M'[b] = carry + excl prefix; tot[b] = sum       [t<16, 1024-slices]
// phase3: out = Q*M'^T + causal diag S*K [t<16]; out2 [t==16]
__global__ __launch_bounds__(256, 1) void k_fused(
    const float* __restrict__ Q, const float* __restrict__ K,
    const float* __restrict__ carry, u16* __restrict__ G,
    u16* __restrict__ Mp, float* __restrict__ tot, unsigned* __restrict__ flg,
    float* __restrict__ out, float* __restrict__ out2) {
  const int t = blockIdx.x, b = blockIdx.y;
  const int tid = threadIdx.x;
  const int w = tid >> 6, l = tid & 63, lr = l & 15, lg = l >> 4;
  const int wr = (w & 1) * 16, wc = (w >> 1) * 64, sc0 = (w >> 1) * 16;
  const int r0 = t * 32;

  __shared__ u16 sh[5632];  // phase1: [32][LDG]; phase3: [32][LDO] + sl[32][40]

  fvec4 pf[4];  // K chunk, held in regs across phases
  v8bf qf[4];   // Q A-frags, held across phases

  // ---------------- phase 1: Gram ----------------
  if (t < 16) {
    load_chunk(K + (size_t)(b * C_ + r0) * D_, tid, pf);
    const float* qrow = Q + (size_t)(b * C_ + r0 + wr + lr) * D_;
#pragma unroll
    for (int kk = 0; kk < 4; ++kk) {
      const float* p = qrow + kk * 32 + 8 * lg;
      fvec4 a = *(const fvec4*)p;
      fvec4 c2 = *(const fvec4*)(p + 4);
      u16 tmp[8] = {f2bf(a[0]),  f2bf(a[1]),  f2bf(a[2]),  f2bf(a[3]),
                    f2bf(c2[0]), f2bf(c2[1]), f2bf(c2[2]), f2bf(c2[3])};
      qf[kk] = *(const v8bf*)tmp;
    }
    lds_put<LDG>(pf, sh, tid);
    __syncthreads();
    v8bf fr[8];
#pragma unroll
    for (int n = 0; n < 8; ++n) {
      u16 tmp[8];
#pragma unroll
      for (int e = 0; e < 8; ++e) tmp[e] = sh[(8 * lg + e) * LDG + 16 * n + lr];
      fr[n] = *(const v8bf*)tmp;
    }
    u16* Gp = G + (size_t)(b * 16 + t) * 16384;
#pragma unroll
    for (int mi = 0; mi < 2; ++mi) {
      v8bf am = fr[2 * w + mi];
#pragma unroll
      for (int n = 0; n < 8; ++n) {
        v4f z = {0.f, 0.f, 0.f, 0.f};
        v4f a = __builtin_amdgcn_mfma_f32_16x16x32_bf16(am, fr[n], z, 0, 0, 0);
#pragma unroll
        for (int j = 0; j < 4; ++j)
          Gp[(size_t)(32 * w + 16 * mi + 4 * lg + j) * 128 + 16 * n + lr] =
              f2bf(a[j]);
      }
    }
  }

  spin_barrier(&flg[0], 136u);

  // ------------- phase 2: prefix (128 blocks, 1024-elem slices) -------------
  if (t < 16) {
    const int e0 = t * 1024 + tid * 4;
    fvec4 c4 = *(const fvec4*)(carry + e0);
    float run0 = 0.f, run1 = 0.f, run2 = 0.f, run3 = 0.f;
    const u16* gb = G + (size_t)b * 16 * 16384 + e0;
    u16* mb = Mp + (size_t)b * 16 * 16384 + e0;
#pragma unroll
    for (int tp = 0; tp < 16; ++tp) {
      u16x4 g = *(const u16x4*)(gb + (size_t)tp * 16384);
      u16x4 m = {f2bf(c4[0] + run0), f2bf(c4[1] + run1), f2bf(c4[2] + run2),
                 f2bf(c4[3] + run3)};
      *(u16x4*)(mb + (size_t)tp * 16384) = m;
      run0 += bf2f(g[0]);
      run1 += bf2f(g[1]);
      run2 += bf2f(g[2]);
      run3 += bf2f(g[3]);
    }
    fvec4 rr = {run0, run1, run2, run3};
    *(fvec4*)(tot + (size_t)b * 16384 + e0) = rr;
  }

  spin_barrier(&flg[1], 136u);

  // ---------------- phase 3: outputs ----------------
  if (t == 16) {  // out2 = carry + mean_b(tot)
    const int e0 = b * 2048 + tid * 8;
    fvec4 s0 = {0.f, 0.f, 0.f, 0.f}, s1 = {0.f, 0.f, 0.f, 0.f};
#pragma unroll
    for (int bb = 0; bb < 8; ++bb) {
      s0 += *(const fvec4*)(tot + (size_t)bb * 16384 + e0);
      s1 += *(const fvec4*)(tot + (size_t)bb * 16384 + e0 + 4);
    }
    fvec4 c0 = *(const fvec4*)(carry + e0);
    fvec4 c1 = *(const fvec4*)(carry + e0 + 4);
    *(fvec4*)(out2 + e0) = c0 + 0.125f * s0;
    *(fvec4*)(out2 + e0 + 4) = c1 + 0.125f * s1;
    return;
  }

  u16* ks = sh;             // [32][LDO]
  u16* sl = sh + 32 * LDO;  // [32][40]

  lds_put<LDO>(pf, ks, tid);

  // M' B-frags: direct bf16 b128 global loads (16 in flight)
  v8bf mf[16];
  {
    const u16* mp = Mp + (size_t)(b * 16 + t) * 16384;
#pragma unroll
    for (int kk = 0; kk < 4; ++kk)
#pragma unroll
      for (int n = 0; n < 4; ++n)
        mf[kk * 4 + n] = *(const v8bf*)(mp + (size_t)(wc + 16 * n + lr) * 128 +
                                        32 * kk + 8 * lg);
  }
  __syncthreads();

  // S-step B-frags: row-major b128 LDS reads
  v8bf sb[4];
#pragma unroll
  for (int kk = 0; kk < 4; ++kk)
    sb[kk] = *(const v8bf*)&ks[(sc0 + lr) * LDO + 32 * kk + 8 * lg];

  // PV B-frags: transposed LDS gather
  v8bf pb[4];
#pragma unroll
  for (int n = 0; n < 4; ++n) {
    u16 tmp[8];
#pragma unroll
    for (int e = 0; e < 8; ++e)
      tmp[e] = ks[(8 * lg + e) * LDO + wc + 16 * n + lr];
    pb[n] = *(const v8bf*)tmp;
  }

  // S tile = Q * Kchunk^T (diagonal, causal mask), hand off via LDS
  v4f sacc = {0.f, 0.f, 0.f, 0.f};
#pragma unroll
  for (int kk = 0; kk < 4; ++kk)
    sacc =
        __builtin_amdgcn_mfma_f32_16x16x32_bf16(qf[kk], sb[kk], sacc, 0, 0, 0);
#pragma unroll
  for (int j = 0; j < 4; ++j) {
    const int sr = wr + lg * 4 + j;
    const int sc = sc0 + lr;
    float v = sacc[j];
    if (sc > sr) v = 0.f;
    sl[sr * 40 + sc] = f2bf(v);
  }

  // acc = Q * M'^T (M' includes carry) — overlaps the barrier wait
  v4f acc[4] = {{0.f, 0.f, 0.f, 0.f}, {0.f, 0.f, 0.f, 0.f},
                {0.f, 0.f, 0.f, 0.f}, {0.f, 0.f, 0.f, 0.f}};
#pragma unroll
  for (int kk = 0; kk < 4; ++kk)
#pragma unroll
    for (int n = 0; n < 4; ++n)
      acc[n] = __builtin_amdgcn_mfma_f32_16x16x32_bf16(qf[kk], mf[kk * 4 + n],
                                                       acc[n], 0, 0, 0);
  __syncthreads();

  // PV: acc += S * Kchunk
  v8bf af = *(const v8bf*)&sl[(wr + lr) * 40 + lg * 8];
#pragma unroll
  for (int n = 0; n < 4; ++n)
    acc[n] =
        __builtin_amdgcn_mfma_f32_16x16x32_bf16(af, pb[n], acc[n], 0, 0, 0);

  // epilogue: C/D layout col = lane&15, row = 4*(lane>>4)+j
#pragma unroll
  for (int n = 0; n < 4; ++n)
#pragma unroll
    for (int j = 0; j < 4; ++j)
      out[(size_t)(b * C_ + r0 + wr + lg * 4 + j) * D_ + wc + n * 16 + lr] =
          acc[n][j];
}

// ================= round-6 three-kernel path (fallback) ====================
__global__ __launch_bounds__(256, 1) void k_gram(const float* __restrict__ K,
                                                 u16* __restrict__ G) {
  const int t = blockIdx.x, b = blockIdx.y;
  const int tid = threadIdx.x;
  const int w = tid >> 6, l = tid & 63, lr = l & 15, lg = l >> 4;

  __shared__ u16 ks[32 * LDG];

  fvec4 pf[4];
  load_chunk(K + (size_t)(b * C_ + t * 32) * D_, tid, pf);
  lds_put<LDG>(pf, ks, tid);
  __syncthreads();

  v8bf fr[8];
#pragma unroll
  for (int n = 0; n < 8; ++n) {
    u16 tmp[8];
#pragma unroll
    for (int e = 0; e < 8; ++e) tmp[e] = ks[(8 * lg + e) * LDG + 16 * n + lr];
    fr[n] = *(const v8bf*)tmp;
  }
  u16* Gp = G + (size_t)(b * 16 + t) * 16384;
#pragma unroll
  for (int mi = 0; mi < 2; ++mi) {
    v8bf am = fr[2 * w + mi];
#pragma unroll
    for (int n = 0; n < 8; ++n) {
      v4f z = {0.f, 0.f, 0.f, 0.f};
      v4f a = __builtin_amdgcn_mfma_f32_16x16x32_bf16(am, fr[n], z, 0, 0, 0);
#pragma unroll
      for (int j = 0; j < 4; ++j)
        Gp[(size_t)(32 * w + 16 * mi + 4 * lg + j) * 128 + 16 * n + lr] =
            f2bf(a[j]);
    }
  }
}

__global__ __launch_bounds__(256, 1) void k_prefix(
    const u16* __restrict__ G, const float* __restrict__ carry,
    u16* __restrict__ Mp, float* __restrict__ tot) {
  const int b = blockIdx.y;
  const int e0 = blockIdx.x * 2048 + threadIdx.x * 8;
  fvec4 c0 = *(const fvec4*)(carry + e0);
  fvec4 c1 = *(const fvec4*)(carry + e0 + 4);
  float c[8] = {c0[0], c0[1], c0[2], c0[3], c1[0], c1[1], c1[2], c1[3]};
  float run[8] = {0.f, 0.f, 0.f, 0.f, 0.f, 0.f, 0.f, 0.f};
  const u16* gb = G + (size_t)b * 16 * 16384 + e0;
  u16* mb = Mp + (size_t)b * 16 * 16384 + e0;
#pragma unroll
  for (int t = 0; t < 16; ++t) {
    u16x8 g = *(const u16x8*)(gb + (size_t)t * 16384);
    u16x8 m;
#pragma unroll
    for (int i = 0; i < 8; ++i) m[i] = f2bf(c[i] + run[i]);
    *(u16x8*)(mb + (size_t)t * 16384) = m;
#pragma unroll
    for (int i = 0; i < 8; ++i) run[i] += bf2f(g[i]);
  }
  fvec4 r0 = {run[0], run[1], run[2], run[3]};
  fvec4 r1 = {run[4], run[5], run[6], run[7]};
  *(fvec4*)(tot + (size_t)b * 16384 + e0) = r0;
  *(fvec4*)(tot + (size_t)b * 16384 + e0 + 4) = r1;
}

__global__ __launch_bounds__(256, 1) void k_out(
    const float* __restrict__ Q, const float* __restrict__ K,
    const u16* __restrict__ Mp, const float* __restrict__ tot,
    const float* __restrict__ carry, float* __restrict__ out,
    float* __restrict__ out2) {
  const int t = blockIdx.x, b = blockIdx.y;
  const int tid = threadIdx.x;

  if (t == 16) {
    const int e0 = b * 2048 + tid * 8;
    fvec4 s0 = {0.f, 0.f, 0.f, 0.f}, s1 = {0.f, 0.f, 0.f, 0.f};
#pragma unroll
    for (int bb = 0; bb < 8; ++bb) {
      s0 += *(const fvec4*)(tot + (size_t)bb * 16384 + e0);
      s1 += *(const fvec4*)(tot + (size_t)bb * 16384 + e0 + 4);
    }
    fvec4 c0 = *(const fvec4*)(carry + e0);
    fvec4 c1 = *(const fvec4*)(carry + e0 + 4);
    *(fvec4*)(out2 + e0) = c0 + 0.125f * s0;
    *(fvec4*)(out2 + e0 + 4) = c1 + 0.125f * s1;
    return;
  }

  const int w = tid >> 6, l = tid & 63, lr = l & 15, lg = l >> 4;
  const int wr = (w & 1) * 16, wc = (w >> 1) * 64, sc0 = (w >> 1) * 16;
  const int r0 = t * 32;

  __shared__ u16 ks[32 * LDO];
  __shared__ u16 sl[32 * 40];

  fvec4 pf[4];
  load_chunk(K + (size_t)(b * C_ + r0) * D_, tid, pf);

  v8bf qf[4];
  {
    const float* qrow = Q + (size_t)(b * C_ + r0 + wr + lr) * D_;
#pragma unroll
    for (int kk = 0; kk < 4; ++kk) {
      const float* p = qrow + kk * 32 + 8 * lg;
      fvec4 a = *(const fvec4*)p;
      fvec4 c2 = *(const fvec4*)(p + 4);
      u16 tmp[8] = {f2bf(a[0]),  f2bf(a[1]),  f2bf(a[2]),  f2bf(a[3]),
                    f2bf(c2[0]), f2bf(c2[1]), f2bf(c2[2]), f2bf(c2[3])};
      qf[kk] = *(const v8bf*)tmp;
    }
  }

  v8bf mf[16];
  {
    const u16* mp = Mp + (size_t)(b * 16 + t) * 16384;
#pragma unroll
    for (int kk = 0; kk < 4; ++kk)
#pragma unroll
      for (int n = 0; n < 4; ++n)
        mf[kk * 4 + n] = *(const v8bf*)(mp + (size_t)(wc + 16 * n + lr) * 128 +
                                        32 * kk + 8 * lg);
  }

  lds_put<LDO>(pf, ks, tid);
  __syncthreads();

  v8bf sb[4];
#pragma unroll
  for (int kk = 0; kk < 4; ++kk)
    sb[kk] = *(const v8bf*)&ks[(sc0 + lr) * LDO + 32 * kk + 8 * lg];

  v8bf pb[4];
#pragma unroll
  for (int n = 0; n < 4; ++n) {
    u16 tmp[8];
#pragma unroll
    for (int e = 0; e < 8; ++e)
      tmp[e] = ks[(8 * lg + e) * LDO + wc + 16 * n + lr];
    pb[n] = *(const v8bf*)tmp;
  }

  v4f sacc = {0.f, 0.f, 0.f, 0.f};
#pragma unroll
  for (int kk = 0; kk < 4; ++kk)
    sacc =
        __builtin_amdgcn_mfma_f32_16x16x32_bf16(qf[kk], sb[kk], sacc, 0, 0, 0);
#pragma unroll
  for (int j = 0; j < 4; ++j) {
    const int sr = wr + lg * 4 + j;
    const int sc = sc0 + lr;
    float v = sacc[j];
    if (sc > sr) v = 0.f;
    sl[sr * 40 + sc] = f2bf(v);
  }

  v4f acc[4] = {{0.f, 0.f, 0.f, 0.f}, {0.f, 0.f, 0.f, 0.f},
                {0.f, 0.f, 0.f, 0.f}, {0.f, 0.f, 0.f, 0.f}};
#pragma unroll
  for (int kk = 0; kk < 4; ++kk)
#pragma unroll
    for (int n = 0; n < 4; ++n)
      acc[n] = __builtin_amdgcn_mfma_f32_16x16x32_bf16(qf[kk], mf[kk * 4 + n],
                                                       acc[n], 0, 0, 0);
  __syncthreads();

  v8bf af = *(const v8bf*)&sl[(wr + lr) * 40 + lg * 8];
#pragma unroll
  for (int n = 0; n < 4; ++n)
    acc[n] =
        __builtin_amdgcn_mfma_f32_16x16x32_bf16(af, pb[n], acc[n], 0, 0, 0);

#pragma unroll
  for (int n = 0; n < 4; ++n)
#pragma unroll
    for (int j = 0; j < 4; ++j)
      out[(size_t)(b * C_ + r0 + wr + lg * 4 + j) * D_ + wc + n * 16 + lr] =
          acc[n][j];
}

extern "C" void kernel_launch(void* const* d_in, const int* in_sizes, int n_in,
                              void* d_out, int out_size, void* d_ws,
                              size_t ws_size, hipStream_t stream) {
  const float* Q = (const float*)d_in[0];
  const float* K = (const float*)d_in[1];
  const float* carry = (const float*)d_in[2];
  float* out = (float*)d_out;
  float* out2 = out + (size_t)B_ * C_ * D_;

  // ws: G bf16 | M' bf16 | tot f32 | flags (2 x u32)
  const size_t nGu = (size_t)128 * 16384;               // u16 elems (G, M')
  const size_t bytesG = nGu * sizeof(u16);              // 4 MiB
  const size_t bytesTot = (size_t)8 * 16384 * sizeof(float);  // 512 KiB
  const size_t flagOff = 2 * bytesG + bytesTot;
  const size_t need = flagOff + 128;

  u16* G = (u16*)d_ws;
  u16* Mp = G + nGu;
  float* tot = (float*)(Mp + nGu);
  unsigned* flg = (unsigned*)((char*)d_ws + flagOff);

  if (ws_size >= need) {
    hipMemsetAsync(flg, 0, 2 * sizeof(unsigned), stream);
    k_fused<<<dim3(17, 8), 256, 0, stream>>>(Q, K, carry, G, Mp, tot, flg, out,
                                             out2);
  } else if (ws_size >= 2 * bytesG + bytesTot) {
    k_gram<<<dim3(16, 8), 256, 0, stream>>>(K, G);
    k_prefix<<<dim3(8, 8), 256, 0, stream>>>(G, carry, Mp, tot);
    k_out<<<dim3(17, 8), 256, 0, stream>>>(Q, K, Mp, tot, carry, out, out2);
  }
}